// Round 1
// baseline (556.253 us; speedup 1.0000x reference)
//
#include <hip/hip_runtime.h>
#include <hip/hip_bf16.h>
#include <cstdint>
#include <math.h>

typedef int v4i __attribute__((ext_vector_type(4)));

// ---------------- float atomic min/max via int tricks ----------------
__device__ __forceinline__ void atomicMinF(float* addr, float v) {
  if (v >= 0.f) atomicMin((int*)addr, __float_as_int(v));
  else          atomicMax((unsigned int*)addr, __float_as_uint(v));
}
__device__ __forceinline__ void atomicMaxF(float* addr, float v) {
  if (v >= 0.f) atomicMax((int*)addr, __float_as_int(v));
  else          atomicMin((unsigned int*)addr, __float_as_uint(v));
}

// ---------------- init params block (ws poisoned 0xAA every call) ----------------
__global__ void init_params_kernel(float* p) {
  p[0] =  INFINITY;  // xmin
  p[1] = -INFINITY;  // xmax
  p[2] =  INFINITY;  // wmin
  p[3] = -INFINITY;  // wmax
}

// ---------------- global min/max, vectorized, block-reduced ----------------
__global__ __launch_bounds__(256) void minmax_kernel(const float* __restrict__ a, long long n,
                                                     float* mnp, float* mxp) {
  float mn = INFINITY, mx = -INFINITY;
  long long n4 = n >> 2;
  long long stride = (long long)gridDim.x * blockDim.x;
  for (long long i = (long long)blockIdx.x * blockDim.x + threadIdx.x; i < n4; i += stride) {
    float4 v = ((const float4*)a)[i];
    mn = fminf(mn, fminf(fminf(v.x, v.y), fminf(v.z, v.w)));
    mx = fmaxf(mx, fmaxf(fmaxf(v.x, v.y), fmaxf(v.z, v.w)));
  }
  if (blockIdx.x == 0 && threadIdx.x < (int)(n & 3)) {
    float v = a[n4 * 4 + threadIdx.x];
    mn = fminf(mn, v); mx = fmaxf(mx, v);
  }
  #pragma unroll
  for (int off = 32; off; off >>= 1) {
    mn = fminf(mn, __shfl_xor(mn, off));
    mx = fmaxf(mx, __shfl_xor(mx, off));
  }
  __shared__ float smn[4], smx[4];
  int wv = threadIdx.x >> 6;
  if ((threadIdx.x & 63) == 0) { smn[wv] = mn; smx[wv] = mx; }
  __syncthreads();
  if (threadIdx.x == 0) {
    mn = fminf(fminf(smn[0], smn[1]), fminf(smn[2], smn[3]));
    mx = fmaxf(fmaxf(smx[0], smx[1]), fmaxf(smx[2], smx[3]));
    atomicMinF(mnp, mn);
    atomicMaxF(mxp, mx);
  }
}

// ---------------- scalar quant params (mirrors reference exactly) ----------------
__global__ void compute_params_kernel(float* p, const int* bits, float Kf) {
  float n   = (float)((1u << bits[0]) - 1u);      // 2^bits - 1, exact
  float xmn = p[0], xmx = p[1], wmn = p[2], wmx = p[3];
  float S1 = (wmx - wmn) / n;
  float Z1 = rintf(n * wmn / (wmn - wmx));
  float S2 = (xmx - xmn) / n;
  float Z2 = rintf(n * xmn / (xmn - xmx));
  float s1s2 = S1 * S2;
  p[4]  = s1s2;
  p[5]  = 128.0f - Z2;                    // multiplies rowsum(q1)[o]
  p[6]  = 128.0f - Z1;                    // multiplies rowsum(xq)[i]
  p[7]  = (Z1 * Z2 - 16384.0f) * Kf;      // constant term
  p[8]  = S2;
  p[9]  = Z2;
  p[10] = wmn;
  p[11] = wmx - wmn;
  p[12] = n;
}

// ---------------- quantize W row -> int8 (shifted -128), rowsum, col constant ----------------
__global__ __launch_bounds__(256) void quant_w_kernel(const float* __restrict__ W,
                                                      const float* __restrict__ bias,
                                                      const float* __restrict__ p,
                                                      int8_t* __restrict__ q1,
                                                      float* __restrict__ colC, int K) {
  const int o = blockIdx.x;
  const float wmn = p[10], wrng = p[11], n = p[12], s1s2 = p[4], cW = p[5], cC = p[7];
  const float4* Wr = (const float4*)(W + (size_t)o * K);
  unsigned int* qr = (unsigned int*)(q1 + (size_t)o * K);
  int sum = 0;
  const int K4 = K >> 2;
  for (int c = threadIdx.x; c < K4; c += 256) {
    float4 v = Wr[c];
    int q0 = (int)rintf((v.x - wmn) / wrng * n);
    int q1i = (int)rintf((v.y - wmn) / wrng * n);
    int q2 = (int)rintf((v.z - wmn) / wrng * n);
    int q3 = (int)rintf((v.w - wmn) / wrng * n);
    sum += q0 + q1i + q2 + q3;
    qr[c] = ((unsigned)((q0 - 128) & 255))
          | ((unsigned)((q1i - 128) & 255) << 8)
          | ((unsigned)((q2 - 128) & 255) << 16)
          | ((unsigned)((q3 - 128) & 255) << 24);
  }
  #pragma unroll
  for (int off = 32; off; off >>= 1) sum += __shfl_xor(sum, off);
  __shared__ int ps[4];
  if ((threadIdx.x & 63) == 0) ps[threadIdx.x >> 6] = sum;
  __syncthreads();
  if (threadIdx.x == 0) {
    float tot = (float)(ps[0] + ps[1] + ps[2] + ps[3]);
    colC[o] = cW * tot + rintf(bias[o] / s1s2) + cC;
  }
}

// ---------------- quantize x row -> int8 (shifted -128), rowsum, row constant ----------------
__global__ __launch_bounds__(256) void quant_x_kernel(const float* __restrict__ x,
                                                      const float* __restrict__ p,
                                                      int8_t* __restrict__ xq,
                                                      float* __restrict__ rowC, int K) {
  const int i = blockIdx.x;
  const float S2 = p[8], Z2 = p[9], n = p[12], cX = p[6];
  const float4* xr = (const float4*)(x + (size_t)i * K);
  unsigned int* qr = (unsigned int*)(xq + (size_t)i * K);
  int sum = 0;
  const int K4 = K >> 2;
  for (int c = threadIdx.x; c < K4; c += 256) {
    float4 v = xr[c];
    int q0 = (int)fminf(fmaxf(rintf(v.x / S2 + Z2), 0.f), n);
    int q1i = (int)fminf(fmaxf(rintf(v.y / S2 + Z2), 0.f), n);
    int q2 = (int)fminf(fmaxf(rintf(v.z / S2 + Z2), 0.f), n);
    int q3 = (int)fminf(fmaxf(rintf(v.w / S2 + Z2), 0.f), n);
    sum += q0 + q1i + q2 + q3;
    qr[c] = ((unsigned)((q0 - 128) & 255))
          | ((unsigned)((q1i - 128) & 255) << 8)
          | ((unsigned)((q2 - 128) & 255) << 16)
          | ((unsigned)((q3 - 128) & 255) << 24);
  }
  #pragma unroll
  for (int off = 32; off; off >>= 1) sum += __shfl_xor(sum, off);
  __shared__ int ps[4];
  if ((threadIdx.x & 63) == 0) ps[threadIdx.x >> 6] = sum;
  __syncthreads();
  if (threadIdx.x == 0) {
    float tot = (float)(ps[0] + ps[1] + ps[2] + ps[3]);
    rowC[i] = cX * tot;
  }
}

// ---------------- async global->LDS 16B helper ----------------
__device__ __forceinline__ void gload_lds16(const void* g, void* l) {
  __builtin_amdgcn_global_load_lds((const __attribute__((address_space(1))) void*)g,
                                   (__attribute__((address_space(3))) void*)l, 16, 0, 0);
}

// ---------------- int8 MFMA GEMM: C[i,o] = sum_k a[i,k]*w[o,k], fused epilogue ----------------
// BM=BN=128, BK=64, 256 threads = 4 waves (2x2), each wave 64x64 via 4x4 frags of 16x16x64.
__global__ __launch_bounds__(256) void gemm_i8_kernel(const int8_t* __restrict__ xq,
                                                      const int8_t* __restrict__ q1,
                                                      const float* __restrict__ p,
                                                      const float* __restrict__ colC,
                                                      const float* __restrict__ rowC,
                                                      float* __restrict__ out,
                                                      int M, int N, int K) {
  __shared__ int8_t As[128 * 64];   // row-major, 64B rows, 16B segs XOR-swizzled
  __shared__ int8_t Bs[128 * 64];

  const int tid  = threadIdx.x;
  const int lane = tid & 63;
  const int wv   = tid >> 6;       // 0..3
  const int wr   = wv >> 1;        // wave row 0..1
  const int wc   = wv & 1;         // wave col 0..1
  const int bm   = blockIdx.y;
  const int bn   = blockIdx.x;
  const int r15  = lane & 15;
  const int kg   = lane >> 4;

  v4i acc[4][4];
  #pragma unroll
  for (int m = 0; m < 4; ++m)
    #pragma unroll
    for (int n = 0; n < 4; ++n) { v4i z = {0, 0, 0, 0}; acc[m][n] = z; }

  const size_t Abase = (size_t)bm * 128 * K;
  const size_t Bbase = (size_t)bn * 128 * K;
  const int srow = tid >> 2;       // staging row 0..63 (per issue)
  const int sseg = tid & 3;        // staging 16B seg within 64B row
  // read-side swizzle: seg_lds = kg ^ (row & 3); row&3 == r15&3 for all frags
  const int sw = ((kg ^ (r15 & 3)) << 4);

  for (int kt = 0; kt < K; kt += 64) {
    __syncthreads();   // previous iteration's LDS reads done before overwrite
    #pragma unroll
    for (int i = 0; i < 2; ++i) {
      int row = i * 64 + srow;
      int sg  = sseg ^ (row & 3);   // pre-swizzled global source, linear LDS dest
      gload_lds16(xq + Abase + (size_t)row * K + kt + sg * 16,
                  &As[i * 4096 + wv * 1024 + lane * 16]);
      gload_lds16(q1 + Bbase + (size_t)row * K + kt + sg * 16,
                  &Bs[i * 4096 + wv * 1024 + lane * 16]);
    }
    __syncthreads();   // drains vmcnt(0): staged data visible

    v4i af[4], bf[4];
    #pragma unroll
    for (int m = 0; m < 4; ++m)
      af[m] = *(const v4i*)&As[(wr * 64 + m * 16 + r15) * 64 + sw];
    #pragma unroll
    for (int n = 0; n < 4; ++n)
      bf[n] = *(const v4i*)&Bs[(wc * 64 + n * 16 + r15) * 64 + sw];
    #pragma unroll
    for (int m = 0; m < 4; ++m)
      #pragma unroll
      for (int n = 0; n < 4; ++n)
        acc[m][n] = __builtin_amdgcn_mfma_i32_16x16x64_i8(af[m], bf[n], acc[m][n], 0, 0, 0);
  }

  // epilogue: out[i,o] = s1s2 * (dot + colC[o] + rowC[i])
  const float s1s2 = p[4];
  const int orow0 = bm * 128 + wr * 64;
  const int ocol0 = bn * 128 + wc * 64;
  #pragma unroll
  for (int n = 0; n < 4; ++n) {
    const int go = ocol0 + n * 16 + r15;
    const float cc = colC[go];
    #pragma unroll
    for (int m = 0; m < 4; ++m) {
      const int gibase = orow0 + m * 16 + kg * 4;
      #pragma unroll
      for (int r = 0; r < 4; ++r) {
        const int gi = gibase + r;
        out[(size_t)gi * N + go] = s1s2 * ((float)acc[m][n][r] + cc + rowC[gi]);
      }
    }
  }
}

// ---------------- host launch ----------------
extern "C" void kernel_launch(void* const* d_in, const int* in_sizes, int n_in,
                              void* d_out, int out_size, void* d_ws, size_t ws_size,
                              hipStream_t stream) {
  const float* x    = (const float*)d_in[0];
  const float* W    = (const float*)d_in[1];
  const float* b    = (const float*)d_in[2];
  const int*   bits = (const int*)d_in[3];

  const long long xN = in_sizes[0];
  const long long wN = in_sizes[1];
  const int O = in_sizes[2];
  const int K = (int)(wN / O);
  const int M = (int)(xN / K);

  char* ws = (char*)d_ws;
  float* p    = (float*)ws;                       // 64 floats of params
  float* colC = (float*)(ws + 256);               // [O]
  size_t off = 256 + (size_t)O * sizeof(float);
  off = (off + 255) & ~(size_t)255;
  float* rowC = (float*)(ws + off);               // [M]
  off += (size_t)M * sizeof(float);
  off = (off + 255) & ~(size_t)255;
  int8_t* q1 = (int8_t*)(ws + off);               // [O*K] int8 (shifted -128)
  off += (size_t)O * (size_t)K;
  int8_t* xq = (int8_t*)(ws + off);               // [M*K] int8 (shifted -128)

  init_params_kernel<<<1, 1, 0, stream>>>(p);
  minmax_kernel<<<512, 256, 0, stream>>>(x, xN, p + 0, p + 1);
  minmax_kernel<<<512, 256, 0, stream>>>(W, wN, p + 2, p + 3);
  compute_params_kernel<<<1, 1, 0, stream>>>(p, bits, (float)K);
  quant_w_kernel<<<O, 256, 0, stream>>>(W, b, p, q1, colC, K);
  quant_x_kernel<<<M, 256, 0, stream>>>(x, p, xq, rowC, K);

  dim3 grid(O / 128, M / 128);
  gemm_i8_kernel<<<grid, 256, 0, stream>>>(xq, q1, p, colC, rowC, (float*)d_out, M, O, K);
}